// Round 1
// baseline (258.462 us; speedup 1.0000x reference)
//
#include <hip/hip_runtime.h>

// Pipeline:
//  1) cvt_bf16: query,key,Wq,Wk,Wv f32 -> bf16
//  2) gemm_proj<0> x2: q = sp(sp(x@W.T)) -> (nh,l,d) bf16 ; gemm_proj<1>: v -> (nh,chunk,e,s) bf16 (pre-transposed)
//  3) chunk_sums: per (nh,chunk): ST[e][d] = sum_s V[s][e]K[s][d], z[d] = sum_s K[s][d]
//  4) scan_chunks: elementwise exclusive prefix over chunks (in place)
//  5) attn_out: per (nh,chunk): A=tril(QK^T); out = (A V + Q S_prev) / (rowsum(A) + Q z_prev)

using bf16x8 = __attribute__((ext_vector_type(8))) short;
using u16x8  = __attribute__((ext_vector_type(8))) unsigned short;
using f32x4  = __attribute__((ext_vector_type(4))) float;

#define L_SEQ   8192
#define NCHUNK  128
#define RECSZ   4160   // 64*64 + 64 floats

__device__ __forceinline__ float bf2f(unsigned short u) {
  union { unsigned int i; float f; } c; c.i = ((unsigned int)u) << 16; return c.f;
}
__device__ __forceinline__ unsigned short f2bf(float f) {
  union { float f; unsigned int i; } c; c.f = f;
  unsigned int r = c.i + 0x7fffu + ((c.i >> 16) & 1u);
  return (unsigned short)(r >> 16);
}
__device__ __forceinline__ float sp_(float x) {
  return (x > 20.0f) ? x : __logf(1.0f + __expf(x));
}
__device__ __forceinline__ void gll16(const void* g, void* l) {
  __builtin_amdgcn_global_load_lds(
      (const __attribute__((address_space(1))) unsigned int*)g,
      (__attribute__((address_space(3))) unsigned int*)l, 16, 0, 0);
}

__global__ void cvt_bf16(const float* __restrict__ in, unsigned short* __restrict__ out, int n4) {
  int stride = gridDim.x * blockDim.x;
  for (int i = blockIdx.x * blockDim.x + threadIdx.x; i < n4; i += stride) {
    float4 v = ((const float4*)in)[i];
    ushort4 o;
    o.x = f2bf(v.x); o.y = f2bf(v.y); o.z = f2bf(v.z); o.w = f2bf(v.w);
    ((ushort4*)out)[i] = o;
  }
}

// C[m][n] = sum_k A[m][k] * W[n][k]; M=32768, N=K=512. 128x128 tile, BK=64, 4 waves.
template <int MODE>  // 0: sp(sp(.)) -> qk layout (nh,l,d) ; 1: plain -> vt layout (nh,c,e,s)
__global__ __launch_bounds__(256, 2) void gemm_proj(const unsigned short* __restrict__ A,
                                                    const unsigned short* __restrict__ W,
                                                    unsigned short* __restrict__ out) {
  __shared__ char As[16384];
  __shared__ char Bs[16384];
  const int tid  = threadIdx.x;
  const int lane = tid & 63;
  const int wave = tid >> 6;
  const int l15  = lane & 15;
  const int lg   = lane >> 4;
  const int wr   = (wave >> 1) * 64;
  const int wc   = (wave & 1) * 64;
  const int bm   = blockIdx.x * 128;
  const int bn   = blockIdx.y * 128;
  const char* Abytes = (const char*)A;
  const char* Wbytes = (const char*)W;

  f32x4 acc[4][4] = {};

  for (int ks = 0; ks < 8; ++ks) {
#pragma unroll
    for (int it = 0; it < 4; ++it) {
      const int p  = wave * 4096 + it * 1024 + lane * 16;
      const int r  = p >> 7;
      const int cb = (p & 127) ^ ((r & 7) << 4);   // pre-swizzled global source, linear LDS dest
      gll16(Abytes + (size_t)(bm + r) * 1024 + ks * 128 + cb, As + wave * 4096 + it * 1024);
      gll16(Wbytes + (size_t)(bn + r) * 1024 + ks * 128 + cb, Bs + wave * 4096 + it * 1024);
    }
    __syncthreads();
#pragma unroll
    for (int kk = 0; kk < 2; ++kk) {
      const int cb = kk * 64 + lg * 16;
      bf16x8 af[4], bw[4];
#pragma unroll
      for (int mi = 0; mi < 4; ++mi) {
        const int r = wr + mi * 16 + l15;
        af[mi] = *(const bf16x8*)(As + r * 128 + (cb ^ ((r & 7) << 4)));
      }
#pragma unroll
      for (int ni = 0; ni < 4; ++ni) {
        const int r = wc + ni * 16 + l15;
        bw[ni] = *(const bf16x8*)(Bs + r * 128 + (cb ^ ((r & 7) << 4)));
      }
#pragma unroll
      for (int mi = 0; mi < 4; ++mi)
#pragma unroll
        for (int ni = 0; ni < 4; ++ni)
          acc[mi][ni] = __builtin_amdgcn_mfma_f32_16x16x32_bf16(af[mi], bw[ni], acc[mi][ni], 0, 0, 0);
    }
    __syncthreads();
  }

#pragma unroll
  for (int mi = 0; mi < 4; ++mi)
#pragma unroll
    for (int ni = 0; ni < 4; ++ni)
#pragma unroll
      for (int j = 0; j < 4; ++j) {
        const int m = bm + wr + mi * 16 + lg * 4 + j;
        const int n = bn + wc + ni * 16 + l15;
        float x = acc[mi][ni][j];
        const int nb = m >> 13;           // /8192
        const int l  = m & 8191;
        const int h  = n >> 6;
        if (MODE == 0) {
          x = sp_(sp_(x));
          const int d = n & 63;
          out[(((size_t)(nb * 8 + h) * 8192 + l) << 6) + d] = f2bf(x);
        } else {
          const int e = n & 63;
          const int cc = l >> 6, s = l & 63;
          out[(((size_t)((nb * 8 + h) * 128 + cc) * 64 + e) << 6) + s] = f2bf(x);
        }
      }
}

// Per (nh, chunk): ST[e][d] = sum_s V[s][e]*K[s][d]; z[d] = sum_s K[s][d]
__global__ __launch_bounds__(256, 4) void chunk_sums(const unsigned short* __restrict__ kb,
                                                     const unsigned short* __restrict__ vt,
                                                     float* __restrict__ Ssum) {
  const int b  = blockIdx.x;          // nh*128 + c
  const int nh = b >> 7, c = b & 127;
  __shared__ unsigned short Ks[64 * 64];  // [s][d]
  const unsigned short* kch = kb + ((size_t)(nh * L_SEQ + c * 64) << 6);
  const unsigned short* vch = vt + ((size_t)b << 12);  // b*64*64
  const int tid = threadIdx.x;
  ((u16x8*)Ks)[tid]       = ((const u16x8*)kch)[tid];
  ((u16x8*)Ks)[tid + 256] = ((const u16x8*)kch)[tid + 256];
  __syncthreads();

  const int e  = tid >> 2;
  const int db = (tid & 3) << 4;
  const unsigned short* vr = vch + e * 64;
  float acc[16] = {};
#pragma unroll
  for (int sb = 0; sb < 8; ++sb) {
    u16x8 vv8 = *(const u16x8*)(vr + sb * 8);
#pragma unroll
    for (int si = 0; si < 8; ++si) {
      const float vv = bf2f(vv8[si]);
      const int s = sb * 8 + si;
      u16x8 k0 = *(const u16x8*)(Ks + s * 64 + db);
      u16x8 k1 = *(const u16x8*)(Ks + s * 64 + db + 8);
#pragma unroll
      for (int i = 0; i < 8; ++i) acc[i] += vv * bf2f(k0[i]);
#pragma unroll
      for (int i = 0; i < 8; ++i) acc[8 + i] += vv * bf2f(k1[i]);
    }
  }
  float* rec = Ssum + (size_t)b * RECSZ;
#pragma unroll
  for (int i = 0; i < 16; ++i) rec[e * 64 + db + i] = acc[i];
  if (tid < 64) {
    float z = 0.f;
    for (int s = 0; s < 64; ++s) z += bf2f(Ks[s * 64 + tid]);
    rec[4096 + tid] = z;
  }
}

// Elementwise exclusive prefix over 128 chunks, in place. 32*4160 independent scans.
__global__ void scan_chunks(float* __restrict__ Ssum) {
  const int g = blockIdx.x * 256 + threadIdx.x;
  if (g >= 32 * RECSZ) return;
  const int nh = g / RECSZ, idx = g - nh * RECSZ;
  float* p = Ssum + (size_t)nh * NCHUNK * RECSZ + idx;
  float acc = 0.f;
  for (int c = 0; c < NCHUNK; ++c) {
    const float t = *p; *p = acc; acc += t; p += RECSZ;
  }
}

__global__ __launch_bounds__(256, 2) void attn_out(const unsigned short* __restrict__ qb,
                                                   const unsigned short* __restrict__ kb,
                                                   const unsigned short* __restrict__ vt,
                                                   const float* __restrict__ Ssum,
                                                   float* __restrict__ out) {
  const int b  = blockIdx.x;
  const int nh = b >> 7, c = b & 127;
  const int nb = nh >> 3, h = nh & 7;
  __shared__ char Qs[8192], Ks[8192], Vs[8192], STs[16384], Ps[8192];
  __shared__ float zsh[64], dzh[64];
  const int tid = threadIdx.x, lane = tid & 63, wave = tid >> 6;
  const int l15 = lane & 15, lg = lane >> 4;

  const char* qch = (const char*)(qb + ((size_t)(nh * L_SEQ + c * 64) << 6));
  const char* kch = (const char*)(kb + ((size_t)(nh * L_SEQ + c * 64) << 6));
  const char* vch = (const char*)(vt + ((size_t)b << 12));
  const float* rec = Ssum + (size_t)b * RECSZ;
  const char* rb = (const char*)rec;

#pragma unroll
  for (int it = 0; it < 2; ++it) {
    const int p  = wave * 2048 + it * 1024 + lane * 16;
    const int r  = p >> 7;
    const int cb = (p & 127) ^ ((r & 7) << 4);
    const int src = r * 128 + cb;
    gll16(qch + src, Qs + wave * 2048 + it * 1024);
    gll16(kch + src, Ks + wave * 2048 + it * 1024);
    gll16(vch + src, Vs + wave * 2048 + it * 1024);
  }
#pragma unroll
  for (int it = 0; it < 4; ++it) {
    const int p  = wave * 4096 + it * 1024 + lane * 16;
    const int e  = p >> 8;
    const int db = (p & 255) ^ ((e & 7) << 5);
    gll16(rb + e * 256 + db, STs + wave * 4096 + it * 1024);
  }
  if (tid < 64) zsh[tid] = rec[4096 + tid];
  __syncthreads();

  // den_qz[t] = sum_d Q[t][d]*z_prev[d]
  {
    const int t = tid >> 2, p4 = tid & 3;
    float dq = 0.f;
#pragma unroll
    for (int half = 0; half < 2; ++half) {
      const int d0 = p4 * 16 + half * 8;
      const int cb = (d0 * 2) ^ ((t & 7) << 4);
      u16x8 qv = *(const u16x8*)(Qs + t * 128 + cb);
#pragma unroll
      for (int i = 0; i < 8; ++i) dq += bf2f(qv[i]) * zsh[d0 + i];
    }
    dq += __shfl_xor(dq, 1);
    dq += __shfl_xor(dq, 2);
    if (p4 == 0) dzh[t] = dq;
  }
  __syncthreads();

  // Phase 1: A = Q K^T (wave w owns rows 16w..16w+15)
  f32x4 accA[4] = {};
#pragma unroll
  for (int kk = 0; kk < 2; ++kk) {
    const int cb = kk * 64 + lg * 16;
    const int rq = wave * 16 + l15;
    bf16x8 aq = *(const bf16x8*)(Qs + rq * 128 + (cb ^ ((rq & 7) << 4)));
#pragma unroll
    for (int ni = 0; ni < 4; ++ni) {
      const int rk = ni * 16 + l15;
      bf16x8 bk = *(const bf16x8*)(Ks + rk * 128 + (cb ^ ((rk & 7) << 4)));
      accA[ni] = __builtin_amdgcn_mfma_f32_16x16x32_bf16(aq, bk, accA[ni], 0, 0, 0);
    }
  }

  // mask causal, rowsum (on bf16-rounded P for num/den consistency), write P
  float den4[4];
#pragma unroll
  for (int j = 0; j < 4; ++j) {
    const int t = wave * 16 + lg * 4 + j;
    float rs = 0.f;
#pragma unroll
    for (int ni = 0; ni < 4; ++ni) {
      const int s = ni * 16 + l15;
      const float v = (s <= t) ? accA[ni][j] : 0.f;
      const unsigned short pb = f2bf(v);
      rs += bf2f(pb);
      *(unsigned short*)(Ps + t * 128 + ((s * 2) ^ ((t & 7) << 4))) = pb;
    }
    rs += __shfl_xor(rs, 1);
    rs += __shfl_xor(rs, 2);
    rs += __shfl_xor(rs, 4);
    rs += __shfl_xor(rs, 8);
    den4[j] = rs + dzh[t];
  }
  __syncthreads();

  // Phase 2: num = P V + Q S_prev
  f32x4 accO[4] = {};
#pragma unroll
  for (int kk = 0; kk < 2; ++kk) {
    const int cb = kk * 64 + lg * 16;
    const int rp = wave * 16 + l15;
    bf16x8 ap = *(const bf16x8*)(Ps + rp * 128 + (cb ^ ((rp & 7) << 4)));
    bf16x8 aq = *(const bf16x8*)(Qs + rp * 128 + (cb ^ ((rp & 7) << 4)));
#pragma unroll
    for (int ni = 0; ni < 4; ++ni) {
      const int rv = ni * 16 + l15;
      bf16x8 bv = *(const bf16x8*)(Vs + rv * 128 + (cb ^ ((rv & 7) << 4)));
      accO[ni] = __builtin_amdgcn_mfma_f32_16x16x32_bf16(ap, bv, accO[ni], 0, 0, 0);
      const int dbst = kk * 128 + lg * 32;
      const int poff = rv * 256 + (dbst ^ ((rv & 7) << 5));
      f32x4 s0 = *(const f32x4*)(STs + poff);
      f32x4 s1 = *(const f32x4*)(STs + poff + 16);
      bf16x8 bs;
      bs[0] = (short)f2bf(s0[0]); bs[1] = (short)f2bf(s0[1]);
      bs[2] = (short)f2bf(s0[2]); bs[3] = (short)f2bf(s0[3]);
      bs[4] = (short)f2bf(s1[0]); bs[5] = (short)f2bf(s1[1]);
      bs[6] = (short)f2bf(s1[2]); bs[7] = (short)f2bf(s1[3]);
      accO[ni] = __builtin_amdgcn_mfma_f32_16x16x32_bf16(aq, bs, accO[ni], 0, 0, 0);
    }
  }

#pragma unroll
  for (int ni = 0; ni < 4; ++ni) {
    const int e = ni * 16 + l15;
#pragma unroll
    for (int j = 0; j < 4; ++j) {
      const int t = wave * 16 + lg * 4 + j;
      out[((size_t)(nb * L_SEQ + c * 64 + t) << 9) + h * 64 + e] = accO[ni][j] / den4[j];
    }
  }
}

extern "C" void kernel_launch(void* const* d_in, const int* in_sizes, int n_in,
                              void* d_out, int out_size, void* d_ws, size_t ws_size,
                              hipStream_t stream) {
  (void)in_sizes; (void)n_in; (void)out_size; (void)ws_size;
  const float* query = (const float*)d_in[0];
  const float* key   = (const float*)d_in[1];
  const float* Wq    = (const float*)d_in[2];
  const float* Wk    = (const float*)d_in[3];
  const float* Wv    = (const float*)d_in[4];
  float* out = (float*)d_out;
  char* ws = (char*)d_ws;

  unsigned short* qb  = (unsigned short*)(ws);              // 33,554,432 B  (nh,l,d) bf16
  unsigned short* kb  = (unsigned short*)(ws + 33554432);   // 33,554,432 B
  unsigned short* vt  = (unsigned short*)(ws + 67108864);   // 33,554,432 B  (nh,c,e,s) bf16
  unsigned short* qbf = (unsigned short*)(ws + 100663296);  // 33,554,432 B  (aliased w/ Ssum)
  unsigned short* kbf = (unsigned short*)(ws + 134217728);  // 33,554,432 B  (aliased w/ Ssum)
  float*          Ssum = (float*)(ws + 100663296);          // 68,157,440 B  (after GEMMs)
  unsigned short* wqb = (unsigned short*)(ws + 168820736);
  unsigned short* wkb = (unsigned short*)(ws + 169345024);
  unsigned short* wvb = (unsigned short*)(ws + 169869312);  // end: 170,393,600 B

  cvt_bf16<<<dim3(2048), dim3(256), 0, stream>>>(query, qbf, 4194304);
  cvt_bf16<<<dim3(2048), dim3(256), 0, stream>>>(key,   kbf, 4194304);
  cvt_bf16<<<dim3(256),  dim3(256), 0, stream>>>(Wq, wqb, 65536);
  cvt_bf16<<<dim3(256),  dim3(256), 0, stream>>>(Wk, wkb, 65536);
  cvt_bf16<<<dim3(256),  dim3(256), 0, stream>>>(Wv, wvb, 65536);

  dim3 gg(256, 4);
  gemm_proj<0><<<gg, dim3(256), 0, stream>>>(qbf, wqb, qb);
  gemm_proj<0><<<gg, dim3(256), 0, stream>>>(kbf, wkb, kb);
  gemm_proj<1><<<gg, dim3(256), 0, stream>>>(kbf, wvb, vt);

  chunk_sums<<<dim3(4096), dim3(256), 0, stream>>>(kb, vt, Ssum);
  scan_chunks<<<dim3(520), dim3(256), 0, stream>>>(Ssum);
  attn_out<<<dim3(4096), dim3(256), 0, stream>>>(qb, kb, vt, Ssum, out);
}

// Round 3
// 203.720 us; speedup vs baseline: 1.2687x; 1.2687x over previous
//
#include <hip/hip_runtime.h>

// Pipeline:
//  1) cvt_all: query,key,Wq,Wk,Wv f32 -> bf16 (single launch)
//  2) gemm_proj<0> x2: q/k = sp(sp(x@W.T)) -> (nh,l,d) bf16 ; gemm_proj<1>: v -> (nh,chunk,e,s) bf16 (pre-transposed)
//  3) chunk_sums (MFMA): per (nh,chunk): ST[e][d] = sum_s V[s][e]K[s][d] (bf16), z[d] = sum_s K[s][d] (f32)
//  4) scan_chunks: elementwise exclusive prefix over chunks (bf16 payload, f32 accum; z in f32)
//  5) attn_out: per (nh,chunk): A=tril(QK^T); out = (A V + Q S_prev) / (rowsum(A) + Q z_prev)

using bf16x8 = __attribute__((ext_vector_type(8))) short;
using u16x8  = __attribute__((ext_vector_type(8))) unsigned short;
using f32x4  = __attribute__((ext_vector_type(4))) float;

#define L_SEQ   8192
#define NCHUNK  128
#define RECB    8448   // bytes: 4096 bf16 ST + 64 f32 z

__device__ __forceinline__ float bf2f(unsigned short u) {
  union { unsigned int i; float f; } c; c.i = ((unsigned int)u) << 16; return c.f;
}
__device__ __forceinline__ unsigned short f2bf(float f) {
  union { float f; unsigned int i; } c; c.f = f;
  unsigned int r = c.i + 0x7fffu + ((c.i >> 16) & 1u);
  return (unsigned short)(r >> 16);
}
__device__ __forceinline__ float sp_(float x) {
  return (x > 20.0f) ? x : __logf(1.0f + __expf(x));
}
__device__ __forceinline__ void gll16(const void* g, void* l) {
  __builtin_amdgcn_global_load_lds(
      (const __attribute__((address_space(1))) unsigned int*)g,
      (__attribute__((address_space(3))) unsigned int*)l, 16, 0, 0);
}

// segment boundaries in float4 units:
//   q  [0,        4194304)   : 4*8192*512 floats / 4
//   k  [4194304,  8388608)
//   wq [8388608,  8454144)   : 512*512/4 = 65536 float4 each
//   wk [8454144,  8519680)
//   wv [8519680,  8585216)
__global__ void cvt_all(const float* __restrict__ q, const float* __restrict__ k,
                        const float* __restrict__ wq, const float* __restrict__ wk,
                        const float* __restrict__ wv,
                        unsigned short* __restrict__ qo, unsigned short* __restrict__ ko,
                        unsigned short* __restrict__ wqo, unsigned short* __restrict__ wko,
                        unsigned short* __restrict__ wvo) {
  const int stride = gridDim.x * blockDim.x;
  for (int i = blockIdx.x * blockDim.x + threadIdx.x; i < 8585216; i += stride) {
    const float* src; unsigned short* dst; int off;
    if (i < 4194304)      { src = q;  dst = qo;  off = i; }
    else if (i < 8388608) { src = k;  dst = ko;  off = i - 4194304; }
    else if (i < 8454144) { src = wq; dst = wqo; off = i - 8388608; }
    else if (i < 8519680) { src = wk; dst = wko; off = i - 8454144; }
    else                  { src = wv; dst = wvo; off = i - 8519680; }
    float4 v = ((const float4*)src)[off];
    ushort4 o;
    o.x = f2bf(v.x); o.y = f2bf(v.y); o.z = f2bf(v.z); o.w = f2bf(v.w);
    ((ushort4*)dst)[off] = o;
  }
}

// C[m][n] = sum_k A[m][k] * W[n][k]; M=32768, N=K=512. 128x128 tile, BK=64, 4 waves.
template <int MODE>  // 0: sp(sp(.)) -> qk layout (nh,l,d) ; 1: plain -> vt layout (nh,c,e,s)
__global__ __launch_bounds__(256, 2) void gemm_proj(const unsigned short* __restrict__ A,
                                                    const unsigned short* __restrict__ W,
                                                    unsigned short* __restrict__ out) {
  __shared__ char As[16384];
  __shared__ char Bs[16384];
  const int tid  = threadIdx.x;
  const int lane = tid & 63;
  const int wave = tid >> 6;
  const int l15  = lane & 15;
  const int lg   = lane >> 4;
  const int wr   = (wave >> 1) * 64;
  const int wc   = (wave & 1) * 64;
  const int bm   = blockIdx.x * 128;
  const int bn   = blockIdx.y * 128;
  const char* Abytes = (const char*)A;
  const char* Wbytes = (const char*)W;

  f32x4 acc[4][4] = {};

  for (int ks = 0; ks < 8; ++ks) {
#pragma unroll
    for (int it = 0; it < 4; ++it) {
      const int p  = wave * 4096 + it * 1024 + lane * 16;
      const int r  = p >> 7;
      const int cb = (p & 127) ^ ((r & 7) << 4);   // pre-swizzled global source, linear LDS dest
      gll16(Abytes + (size_t)(bm + r) * 1024 + ks * 128 + cb, As + wave * 4096 + it * 1024);
      gll16(Wbytes + (size_t)(bn + r) * 1024 + ks * 128 + cb, Bs + wave * 4096 + it * 1024);
    }
    __syncthreads();
#pragma unroll
    for (int kk = 0; kk < 2; ++kk) {
      const int cb = kk * 64 + lg * 16;
      bf16x8 af[4], bw[4];
#pragma unroll
      for (int mi = 0; mi < 4; ++mi) {
        const int r = wr + mi * 16 + l15;
        af[mi] = *(const bf16x8*)(As + r * 128 + (cb ^ ((r & 7) << 4)));
      }
#pragma unroll
      for (int ni = 0; ni < 4; ++ni) {
        const int r = wc + ni * 16 + l15;
        bw[ni] = *(const bf16x8*)(Bs + r * 128 + (cb ^ ((r & 7) << 4)));
      }
#pragma unroll
      for (int mi = 0; mi < 4; ++mi)
#pragma unroll
        for (int ni = 0; ni < 4; ++ni)
          acc[mi][ni] = __builtin_amdgcn_mfma_f32_16x16x32_bf16(af[mi], bw[ni], acc[mi][ni], 0, 0, 0);
    }
    __syncthreads();
  }

#pragma unroll
  for (int mi = 0; mi < 4; ++mi)
#pragma unroll
    for (int ni = 0; ni < 4; ++ni)
#pragma unroll
      for (int j = 0; j < 4; ++j) {
        const int m = bm + wr + mi * 16 + lg * 4 + j;
        const int n = bn + wc + ni * 16 + l15;
        float x = acc[mi][ni][j];
        const int nb = m >> 13;           // /8192
        const int l  = m & 8191;
        const int h  = n >> 6;
        if (MODE == 0) {
          x = sp_(sp_(x));
          const int d = n & 63;
          out[(((size_t)(nb * 8 + h) * 8192 + l) << 6) + d] = f2bf(x);
        } else {
          const int e = n & 63;
          const int cc = l >> 6, s = l & 63;
          out[(((size_t)((nb * 8 + h) * 128 + cc) * 64 + e) << 6) + s] = f2bf(x);
        }
      }
}

// Per (nh, chunk): ST[e][d] = sum_s Vt[e][s]*K[s][d] via MFMA (in-LDS K transpose); z[d] = sum_s K[s][d]
__global__ __launch_bounds__(256, 4) void chunk_sums(const unsigned short* __restrict__ kb,
                                                     const unsigned short* __restrict__ vt,
                                                     char* __restrict__ S) {
  const int b  = blockIdx.x;          // nh*128 + c
  const int nh = b >> 7, c = b & 127;
  __shared__ char Kt[8192];    // [d][s] bf16, XOR-swizzled rows
  __shared__ char STs[8192];   // [e][d] bf16, linear
  const int tid = threadIdx.x, lane = tid & 63, wave = tid >> 6;
  const int l15 = lane & 15, lg = lane >> 4;
  const unsigned short* kch = kb + ((size_t)(nh * L_SEQ + c * 64) << 6);
  const unsigned short* vch = vt + ((size_t)b << 12);

  // transpose K chunk [s][d] -> Kt[d][s] (swizzled)
  {
    const int s = tid >> 2, d0 = (tid & 3) << 4;
    u16x8 a = *(const u16x8*)(kch + s * 64 + d0);
    u16x8 bb = *(const u16x8*)(kch + s * 64 + d0 + 8);
#pragma unroll
    for (int i = 0; i < 8; ++i) {
      const int d = d0 + i;
      *(unsigned short*)(Kt + d * 128 + ((2 * s) ^ ((d & 7) << 4))) = a[i];
    }
#pragma unroll
    for (int i = 0; i < 8; ++i) {
      const int d = d0 + 8 + i;
      *(unsigned short*)(Kt + d * 128 + ((2 * s) ^ ((d & 7) << 4))) = bb[i];
    }
  }
  __syncthreads();

  // MFMA: wave w -> e-rows 16w..16w+15 ; ST[e][d] = sum_s Vt[e][s]*Kt[d][s]
  f32x4 acc[4] = {};
#pragma unroll
  for (int kk = 0; kk < 2; ++kk) {
    bf16x8 av = *(const bf16x8*)(vch + (wave * 16 + l15) * 64 + kk * 32 + lg * 8);
#pragma unroll
    for (int ni = 0; ni < 4; ++ni) {
      const int d = ni * 16 + l15;
      bf16x8 bk = *(const bf16x8*)(Kt + d * 128 + ((kk * 64 + lg * 16) ^ ((d & 7) << 4)));
      acc[ni] = __builtin_amdgcn_mfma_f32_16x16x32_bf16(av, bk, acc[ni], 0, 0, 0);
    }
  }

  char* rec = S + (size_t)b * RECB;

  // z[d] = sum_s K[s][d] from Kt rows (f32)
  if (tid < 64) {
    float z = 0.f;
#pragma unroll
    for (int kk = 0; kk < 8; ++kk) {
      bf16x8 kv = *(const bf16x8*)(Kt + tid * 128 + ((kk * 16) ^ ((tid & 7) << 4)));
#pragma unroll
      for (int i = 0; i < 8; ++i) z += bf2f(kv[i]);
    }
    *(float*)(rec + 8192 + tid * 4) = z;
  }

  // stage ST to LDS (bf16), then coalesced copy-out
#pragma unroll
  for (int ni = 0; ni < 4; ++ni)
#pragma unroll
    for (int j = 0; j < 4; ++j) {
      const int e = wave * 16 + lg * 4 + j, d = ni * 16 + l15;
      *(unsigned short*)(STs + e * 128 + d * 2) = f2bf(acc[ni][j]);
    }
  __syncthreads();
  {
    const int off = tid * 32;
    *(u16x8*)(rec + off)      = *(const u16x8*)(STs + off);
    *(u16x8*)(rec + off + 16) = *(const u16x8*)(STs + off + 16);
  }
}

// Exclusive prefix over 128 chunks, in place. ST: bf16 payload, f32 accum (paired); z: f32.
__global__ void scan_chunks(char* __restrict__ S) {
  const int g = blockIdx.x * 256 + threadIdx.x;
  if (g < 65536) {                       // 32 nh * 2048 bf16-pairs
    const int nh = g >> 11, pr = g & 2047;
    char* p = S + (size_t)nh * NCHUNK * RECB + pr * 4;
    float a0 = 0.f, a1 = 0.f;
    for (int c = 0; c < NCHUNK; ++c) {
      const unsigned int u = *(unsigned int*)p;
      const float t0 = bf2f((unsigned short)(u & 0xffff));
      const float t1 = bf2f((unsigned short)(u >> 16));
      *(unsigned int*)p = (unsigned int)f2bf(a0) | ((unsigned int)f2bf(a1) << 16);
      a0 += t0; a1 += t1;
      p += RECB;
    }
  } else if (g < 67584) {                // 32 nh * 64 z floats
    const int idx = g - 65536;
    const int nh = idx >> 6, d = idx & 63;
    char* p = S + (size_t)nh * NCHUNK * RECB + 8192 + d * 4;
    float a = 0.f;
    for (int c = 0; c < NCHUNK; ++c) {
      const float t = *(float*)p; *(float*)p = a; a += t; p += RECB;
    }
  }
}

__global__ __launch_bounds__(256, 2) void attn_out(const unsigned short* __restrict__ qb,
                                                   const unsigned short* __restrict__ kb,
                                                   const unsigned short* __restrict__ vt,
                                                   const char* __restrict__ S,
                                                   float* __restrict__ out) {
  const int b  = blockIdx.x;
  const int nh = b >> 7, c = b & 127;
  const int nb = nh >> 3, h = nh & 7;
  __shared__ char Qs[8192], Ks[8192], Vs[8192], STs[8192], Ps[8192];
  __shared__ float zsh[64], dzh[64];
  const int tid = threadIdx.x, lane = tid & 63, wave = tid >> 6;
  const int l15 = lane & 15, lg = lane >> 4;

  const char* qch = (const char*)(qb + ((size_t)(nh * L_SEQ + c * 64) << 6));
  const char* kch = (const char*)(kb + ((size_t)(nh * L_SEQ + c * 64) << 6));
  const char* vch = (const char*)(vt + ((size_t)b << 12));
  const char* rb  = S + (size_t)b * RECB;

#pragma unroll
  for (int it = 0; it < 2; ++it) {
    const int p  = wave * 2048 + it * 1024 + lane * 16;
    const int r  = p >> 7;
    const int cb = (p & 127) ^ ((r & 7) << 4);
    const int src = r * 128 + cb;
    gll16(qch + src, Qs + wave * 2048 + it * 1024);
    gll16(kch + src, Ks + wave * 2048 + it * 1024);
    gll16(vch + src, Vs + wave * 2048 + it * 1024);
    gll16(rb + src,  STs + wave * 2048 + it * 1024);
  }
  if (tid < 64) zsh[tid] = *(const float*)(rb + 8192 + tid * 4);
  __syncthreads();

  // den_qz[t] = sum_d Q[t][d]*z_prev[d]
  {
    const int t = tid >> 2, p4 = tid & 3;
    float dq = 0.f;
#pragma unroll
    for (int half = 0; half < 2; ++half) {
      const int d0 = p4 * 16 + half * 8;
      const int cb = (d0 * 2) ^ ((t & 7) << 4);
      u16x8 qv = *(const u16x8*)(Qs + t * 128 + cb);
#pragma unroll
      for (int i = 0; i < 8; ++i) dq += bf2f(qv[i]) * zsh[d0 + i];
    }
    dq += __shfl_xor(dq, 1);
    dq += __shfl_xor(dq, 2);
    if (p4 == 0) dzh[t] = dq;
  }
  __syncthreads();

  // Phase 1: A = Q K^T (wave w owns rows 16w..16w+15)
  f32x4 accA[4] = {};
#pragma unroll
  for (int kk = 0; kk < 2; ++kk) {
    const int cb = kk * 64 + lg * 16;
    const int rq = wave * 16 + l15;
    bf16x8 aq = *(const bf16x8*)(Qs + rq * 128 + (cb ^ ((rq & 7) << 4)));
#pragma unroll
    for (int ni = 0; ni < 4; ++ni) {
      const int rk = ni * 16 + l15;
      bf16x8 bk = *(const bf16x8*)(Ks + rk * 128 + (cb ^ ((rk & 7) << 4)));
      accA[ni] = __builtin_amdgcn_mfma_f32_16x16x32_bf16(aq, bk, accA[ni], 0, 0, 0);
    }
  }

  // mask causal, rowsum (on bf16-rounded P for num/den consistency), write P
  float den4[4];
#pragma unroll
  for (int j = 0; j < 4; ++j) {
    const int t = wave * 16 + lg * 4 + j;
    float rs = 0.f;
#pragma unroll
    for (int ni = 0; ni < 4; ++ni) {
      const int s = ni * 16 + l15;
      const float v = (s <= t) ? accA[ni][j] : 0.f;
      const unsigned short pb = f2bf(v);
      rs += bf2f(pb);
      *(unsigned short*)(Ps + t * 128 + ((s * 2) ^ ((t & 7) << 4))) = pb;
    }
    rs += __shfl_xor(rs, 1);
    rs += __shfl_xor(rs, 2);
    rs += __shfl_xor(rs, 4);
    rs += __shfl_xor(rs, 8);
    den4[j] = rs + dzh[t];
  }
  __syncthreads();

  // Phase 2: num = P V + Q S_prev  (both B-operands bf16 rows, identical addressing)
  f32x4 accO[4] = {};
#pragma unroll
  for (int kk = 0; kk < 2; ++kk) {
    const int cb = kk * 64 + lg * 16;
    const int rp = wave * 16 + l15;
    bf16x8 ap = *(const bf16x8*)(Ps + rp * 128 + (cb ^ ((rp & 7) << 4)));
    bf16x8 aq = *(const bf16x8*)(Qs + rp * 128 + (cb ^ ((rp & 7) << 4)));
#pragma unroll
    for (int ni = 0; ni < 4; ++ni) {
      const int rv = ni * 16 + l15;
      bf16x8 bv = *(const bf16x8*)(Vs + rv * 128 + (cb ^ ((rv & 7) << 4)));
      bf16x8 bs = *(const bf16x8*)(STs + rv * 128 + (cb ^ ((rv & 7) << 4)));
      accO[ni] = __builtin_amdgcn_mfma_f32_16x16x32_bf16(ap, bv, accO[ni], 0, 0, 0);
      accO[ni] = __builtin_amdgcn_mfma_f32_16x16x32_bf16(aq, bs, accO[ni], 0, 0, 0);
    }
  }

#pragma unroll
  for (int ni = 0; ni < 4; ++ni) {
    const int e = ni * 16 + l15;
#pragma unroll
    for (int j = 0; j < 4; ++j) {
      const int t = wave * 16 + lg * 4 + j;
      out[((size_t)(nb * L_SEQ + c * 64 + t) << 9) + h * 64 + e] = accO[ni][j] / den4[j];
    }
  }
}

extern "C" void kernel_launch(void* const* d_in, const int* in_sizes, int n_in,
                              void* d_out, int out_size, void* d_ws, size_t ws_size,
                              hipStream_t stream) {
  (void)in_sizes; (void)n_in; (void)out_size; (void)ws_size;
  const float* query = (const float*)d_in[0];
  const float* key   = (const float*)d_in[1];
  const float* Wq    = (const float*)d_in[2];
  const float* Wk    = (const float*)d_in[3];
  const float* Wv    = (const float*)d_in[4];
  float* out = (float*)d_out;
  char* ws = (char*)d_ws;

  unsigned short* qb  = (unsigned short*)(ws);              // 33,554,432 B  (nh,l,d) bf16
  unsigned short* kb  = (unsigned short*)(ws + 33554432);   // 33,554,432 B
  unsigned short* vt  = (unsigned short*)(ws + 67108864);   // 33,554,432 B  (nh,c,e,s) bf16
  unsigned short* qbf = (unsigned short*)(ws + 100663296);  // 33,554,432 B  (dead after q-GEMM)
  unsigned short* kbf = (unsigned short*)(ws + 134217728);  // 33,554,432 B  (dead after v-GEMM)
  char*           Ssum = ws + 100663296;                    // 34,603,008 B  (aliased over qbf/kbf)
  unsigned short* wqb = (unsigned short*)(ws + 168820736);
  unsigned short* wkb = (unsigned short*)(ws + 169345024);
  unsigned short* wvb = (unsigned short*)(ws + 169869312);  // end: 170,393,600 B

  cvt_all<<<dim3(2048), dim3(256), 0, stream>>>(query, key, Wq, Wk, Wv, qbf, kbf, wqb, wkb, wvb);

  dim3 gg(256, 4);
  gemm_proj<0><<<gg, dim3(256), 0, stream>>>(qbf, wqb, qb);
  gemm_proj<0><<<gg, dim3(256), 0, stream>>>(kbf, wkb, kb);
  gemm_proj<1><<<gg, dim3(256), 0, stream>>>(kbf, wvb, vt);

  chunk_sums<<<dim3(4096), dim3(256), 0, stream>>>(kb, vt, Ssum);
  scan_chunks<<<dim3(264), dim3(256), 0, stream>>>(Ssum);
  attn_out<<<dim3(4096), dim3(256), 0, stream>>>(qb, kb, vt, Ssum, out);
}